// Round 1
// baseline (7387.266 us; speedup 1.0000x reference)
//
#include <hip/hip_runtime.h>
#include <math.h>

// Problem constants
#define B_ 8192
#define DIN_ 2048
#define H_ 1024
#define V_ 6
#define T_ 6

// GEMM tile
#define BM 128
#define BN 128
#define BK 16

__device__ __forceinline__ float sigmoidf_(float x) {
    return 1.0f / (1.0f + expf(-x));
}

// ---------------------------------------------------------------------------
// init: prev = start_embed (broadcast), rc = 1, nt = 0
// ---------------------------------------------------------------------------
__global__ __launch_bounds__(256) void init_k(const float* __restrict__ se,
                                              float* __restrict__ prev,
                                              float* __restrict__ rc,
                                              float* __restrict__ nt) {
    const int b = blockIdx.x;
    const int tid = threadIdx.x;
    const float4 v = *(const float4*)(se + tid * 4);
    *(float4*)(prev + (size_t)b * H_ + tid * 4) = v;
    if (tid == 0) { rc[b] = 1.0f; nt[b] = 0.0f; }
}

// ---------------------------------------------------------------------------
// Fused GEMM: C = act( A1 @ B[0:1024,:] + A2 @ B[1024:2048,:] + bias )
//   mode 0: encoder           -> C0 = acc + bias            (write h)
//   mode 1: z/r fused         -> bx<8: C0 = sigmoid(acc+bz) (z)
//                                bx>=8: C1 = sigmoid(acc+br) * h (rh)
//   mode 2: h_tilde + update  -> h = (1-z)*h + z*tanh(acc+bh)  (in-place h)
// B matrices are (2048,1024) row-major, N stride = 1024.
// ---------------------------------------------------------------------------
__global__ __launch_bounds__(256, 2)
void gemm_k(const float* __restrict__ A1, int lda1,
            const float* __restrict__ A2, int lda2,
            const float* __restrict__ B0, const float* __restrict__ B1,
            const float* __restrict__ bias0, const float* __restrict__ bias1,
            const float* __restrict__ zbuf, float* __restrict__ hbuf,
            float* __restrict__ C0, float* __restrict__ C1,
            int mode)
{
    __shared__ float As[BK][BM + 4];
    __shared__ float Bs[BK][BN + 4];

    const int tid = threadIdx.x;
    int bx = blockIdx.x;
    const int by = blockIdx.y;

    const float* Bmat = B0;
    const float* bias = bias0;
    int isR = 0;
    if (mode == 1 && bx >= 8) { bx -= 8; Bmat = B1; bias = bias1; isR = 1; }

    const int n0 = bx * BN;
    const int m0 = by * BM;

    const int tx4 = (tid & 15) << 2;         // 0..60
    const int ty4 = ((tid >> 4) & 15) << 2;  // 0..60

    const int ar = tid >> 2;                 // 0..63
    const int ac = (tid & 3) << 2;           // 0,4,8,12
    const int bk = tid >> 4;                 // 0..15
    const int bn = (tid & 15) << 2;          // 0..60

    float acc[8][8];
#pragma unroll
    for (int i = 0; i < 8; ++i)
#pragma unroll
        for (int j = 0; j < 8; ++j) acc[i][j] = 0.0f;

#pragma unroll 1
    for (int half = 0; half < 2; ++half) {
        const float* A = half ? A2 : A1;
        const int lda = half ? lda2 : lda1;
        const float* Bb = Bmat + (size_t)(half * 1024) * H_ + n0;

        const float* aP0 = A + (size_t)(m0 + ar) * lda + ac;
        const float* aP1 = A + (size_t)(m0 + ar + 64) * lda + ac;
        const float* bP  = Bb + (size_t)bk * H_ + bn;

        float4 ra0 = *(const float4*)(aP0);
        float4 ra1 = *(const float4*)(aP1);
        float4 rb0 = *(const float4*)(bP);
        float4 rb1 = *(const float4*)(bP + 64);

#pragma unroll 1
        for (int kt = 0; kt < 64; ++kt) {
            __syncthreads();
            As[ac + 0][ar] = ra0.x;
            As[ac + 1][ar] = ra0.y;
            As[ac + 2][ar] = ra0.z;
            As[ac + 3][ar] = ra0.w;
            As[ac + 0][ar + 64] = ra1.x;
            As[ac + 1][ar + 64] = ra1.y;
            As[ac + 2][ar + 64] = ra1.z;
            As[ac + 3][ar + 64] = ra1.w;
            *(float4*)&Bs[bk][bn] = rb0;
            *(float4*)&Bs[bk][bn + 64] = rb1;
            __syncthreads();

            if (kt < 63) {
                const int ka = (kt + 1) << 4;
                ra0 = *(const float4*)(aP0 + ka);
                ra1 = *(const float4*)(aP1 + ka);
                rb0 = *(const float4*)(bP + (size_t)ka * H_);
                rb1 = *(const float4*)(bP + (size_t)ka * H_ + 64);
            }

#pragma unroll
            for (int k = 0; k < BK; ++k) {
                const float4 a0 = *(const float4*)&As[k][ty4];
                const float4 a1 = *(const float4*)&As[k][ty4 + 64];
                const float4 b0 = *(const float4*)&Bs[k][tx4];
                const float4 b1 = *(const float4*)&Bs[k][tx4 + 64];
                const float av[8] = {a0.x, a0.y, a0.z, a0.w,
                                     a1.x, a1.y, a1.z, a1.w};
                const float bv[8] = {b0.x, b0.y, b0.z, b0.w,
                                     b1.x, b1.y, b1.z, b1.w};
#pragma unroll
                for (int i = 0; i < 8; ++i)
#pragma unroll
                    for (int j = 0; j < 8; ++j)
                        acc[i][j] = fmaf(av[i], bv[j], acc[i][j]);
            }
        }
    }

    // -------- epilogue --------
    const float4 bl = *(const float4*)(bias + n0 + tx4);
    const float4 bh4 = *(const float4*)(bias + n0 + tx4 + 64);
    const float bcol[8] = {bl.x, bl.y, bl.z, bl.w, bh4.x, bh4.y, bh4.z, bh4.w};

#pragma unroll
    for (int i = 0; i < 8; ++i) {
        const int row = m0 + ((i < 4) ? (ty4 + i) : (ty4 + i + 60));
#pragma unroll
        for (int jh = 0; jh < 2; ++jh) {
            const size_t off = (size_t)row * H_ + n0 + tx4 + jh * 64;
            const float r0 = acc[i][jh * 4 + 0] + bcol[jh * 4 + 0];
            const float r1 = acc[i][jh * 4 + 1] + bcol[jh * 4 + 1];
            const float r2 = acc[i][jh * 4 + 2] + bcol[jh * 4 + 2];
            const float r3 = acc[i][jh * 4 + 3] + bcol[jh * 4 + 3];
            float4 o;
            if (mode == 0) {
                o.x = r0; o.y = r1; o.z = r2; o.w = r3;
                *(float4*)(C0 + off) = o;
            } else if (mode == 1) {
                const float s0 = sigmoidf_(r0);
                const float s1 = sigmoidf_(r1);
                const float s2 = sigmoidf_(r2);
                const float s3 = sigmoidf_(r3);
                if (!isR) {
                    o.x = s0; o.y = s1; o.z = s2; o.w = s3;
                    *(float4*)(C0 + off) = o;
                } else {
                    const float4 hv = *(const float4*)(hbuf + off);
                    o.x = s0 * hv.x; o.y = s1 * hv.y;
                    o.z = s2 * hv.z; o.w = s3 * hv.w;
                    *(float4*)(C1 + off) = o;
                }
            } else {
                const float t0 = tanhf(r0);
                const float t1 = tanhf(r1);
                const float t2 = tanhf(r2);
                const float t3 = tanhf(r3);
                const float4 zv = *(const float4*)(zbuf + off);
                const float4 hv = *(const float4*)(hbuf + off);
                o.x = (1.0f - zv.x) * hv.x + zv.x * t0;
                o.y = (1.0f - zv.y) * hv.y + zv.y * t1;
                o.z = (1.0f - zv.z) * hv.z + zv.z * t2;
                o.w = (1.0f - zv.w) * hv.w + zv.w * t3;
                *(float4*)(hbuf + off) = o;
            }
        }
    }
}

// ---------------------------------------------------------------------------
// Per-step token kernel: one wave per batch row.
// logits = h @ W_out + b_out; a = logits + gumbel(u); tok = argmax(a)
// message[b, t*6+v] = (v==tok)? rc : 0; nt += rc; rc *= (tok!=5);
// prev[b,:] = W_tok[tok,:] + b_tok
// ---------------------------------------------------------------------------
__global__ __launch_bounds__(256)
void step_tok(const float* __restrict__ h,
              const float* __restrict__ W_out, const float* __restrict__ b_out,
              const float* __restrict__ u,
              const float* __restrict__ W_tok, const float* __restrict__ b_tok,
              float* __restrict__ rc, float* __restrict__ nt,
              float* __restrict__ prev,
              float* __restrict__ out_msg, float* __restrict__ out_logits,
              float* __restrict__ out_nt, int t)
{
    const int lane = threadIdx.x & 63;
    const int wv = threadIdx.x >> 6;
    const int b = blockIdx.x * 4 + wv;

    const float* hr = h + (size_t)b * H_;
    float s[6] = {0.f, 0.f, 0.f, 0.f, 0.f, 0.f};
#pragma unroll
    for (int i = 0; i < 4; ++i) {
        const int k0 = i * 256 + lane * 4;
        const float4 hv = *(const float4*)(hr + k0);
        const float he[4] = {hv.x, hv.y, hv.z, hv.w};
#pragma unroll
        for (int e = 0; e < 4; ++e) {
            const float* w = W_out + (size_t)(k0 + e) * V_;
            const float xv = he[e];
#pragma unroll
            for (int v = 0; v < 6; ++v) s[v] = fmaf(xv, w[v], s[v]);
        }
    }
#pragma unroll
    for (int m = 1; m < 64; m <<= 1) {
#pragma unroll
        for (int v = 0; v < 6; ++v) s[v] += __shfl_xor(s[v], m, 64);
    }

    float lg[6];
#pragma unroll
    for (int v = 0; v < 6; ++v) lg[v] = s[v] + b_out[v];

    const float* ub = u + (size_t)b * V_;
    const float eps = 1e-10f;
    float aa[6];
#pragma unroll
    for (int v = 0; v < 6; ++v) {
        const float g = -logf(-logf(ub[v] + eps) + eps);
        aa[v] = lg[v] + g;  // TAU = 1
    }
    int tok = 0;
    float best = aa[0];
#pragma unroll
    for (int v = 1; v < 6; ++v)
        if (aa[v] > best) { best = aa[v]; tok = v; }  // first-max, matches jnp.argmax

    const float rco = rc[b];
    if (lane == 0) {
#pragma unroll
        for (int v = 0; v < 6; ++v) out_logits[(size_t)b * 6 + v] = lg[v];
#pragma unroll
        for (int v = 0; v < 6; ++v)
            out_msg[(size_t)b * 36 + t * 6 + v] = (v == tok) ? rco : 0.0f;
        const float ntn = nt[b] + rco;
        nt[b] = ntn;
        out_nt[b] = ntn;
        rc[b] = (tok == 5) ? 0.0f : rco;
    }

    // prev = W_tok[tok] + b_tok (tok uniform across the wave)
    const float* wt = W_tok + (size_t)tok * H_;
    float* pr = prev + (size_t)b * H_;
#pragma unroll
    for (int i = 0; i < 4; ++i) {
        const int c = i * 256 + lane * 4;
        const float4 wv2 = *(const float4*)(wt + c);
        const float4 bt = *(const float4*)(b_tok + c);
        float4 o;
        o.x = wv2.x + bt.x; o.y = wv2.y + bt.y;
        o.z = wv2.z + bt.z; o.w = wv2.w + bt.w;
        *(float4*)(pr + c) = o;
    }
}

// ---------------------------------------------------------------------------
extern "C" void kernel_launch(void* const* d_in, const int* in_sizes, int n_in,
                              void* d_out, int out_size, void* d_ws, size_t ws_size,
                              hipStream_t stream)
{
    (void)in_sizes; (void)n_in; (void)out_size; (void)ws_size;
    const float* x       = (const float*)d_in[0];
    const float* u_noise = (const float*)d_in[1];
    const float* W_enc   = (const float*)d_in[2];
    const float* b_enc   = (const float*)d_in[3];
    const float* start_e = (const float*)d_in[4];
    const float* W_tok   = (const float*)d_in[5];
    const float* b_tok   = (const float*)d_in[6];
    const float* Wz      = (const float*)d_in[7];
    const float* bz      = (const float*)d_in[8];
    const float* Wr      = (const float*)d_in[9];
    const float* br      = (const float*)d_in[10];
    const float* Wh      = (const float*)d_in[11];
    const float* bh      = (const float*)d_in[12];
    const float* W_out   = (const float*)d_in[13];
    const float* b_out   = (const float*)d_in[14];

    float* out = (float*)d_out;
    float* out_msg = out;                                   // (B, T*V)
    float* out_logits = out + (size_t)B_ * T_ * V_;         // (T, B, V)
    float* out_nt = out_logits + (size_t)T_ * B_ * V_;      // (B,)

    float* ws = (float*)d_ws;
    const size_t SZ = (size_t)B_ * H_;
    float* hbuf = ws;
    float* prev = ws + SZ;
    float* zbuf = ws + 2 * SZ;
    float* rhbf = ws + 3 * SZ;
    float* rcb  = ws + 4 * SZ;
    float* ntb  = rcb + B_;

    const dim3 blk(256);

    init_k<<<B_, 256, 0, stream>>>(start_e, prev, rcb, ntb);

    // encoder: h0 = x @ W_enc + b_enc   (x split into two 1024-wide halves)
    gemm_k<<<dim3(8, 64), blk, 0, stream>>>(x, DIN_, x + 1024, DIN_,
        W_enc, nullptr, b_enc, nullptr, nullptr, hbuf, hbuf, nullptr, 0);

    for (int t = 0; t < T_; ++t) {
        // z = sigmoid([prev|h]@Wz + bz); rh = sigmoid([prev|h]@Wr + br) * h
        gemm_k<<<dim3(16, 64), blk, 0, stream>>>(prev, H_, hbuf, H_,
            Wz, Wr, bz, br, nullptr, hbuf, zbuf, rhbf, 1);
        // h = (1-z)*h + z*tanh([prev|rh]@Wh + bh)
        gemm_k<<<dim3(8, 64), blk, 0, stream>>>(prev, H_, rhbf, H_,
            Wh, nullptr, bh, nullptr, zbuf, hbuf, nullptr, nullptr, 2);
        // logits / gumbel argmax / message / rc / nt / prev
        step_tok<<<B_ / 4, 256, 0, stream>>>(hbuf, W_out, b_out,
            u_noise + (size_t)t * B_ * V_, W_tok, b_tok, rcb, ntb, prev,
            out_msg, out_logits + (size_t)t * B_ * V_, out_nt, t);
    }
}

// Round 2
// 2329.398 us; speedup vs baseline: 3.1713x; 3.1713x over previous
//
#include <hip/hip_runtime.h>
#include <math.h>

#define B_ 8192
#define DIN_ 2048
#define H_ 1024
#define V_ 6
#define T_ 6

typedef short bf16x8 __attribute__((ext_vector_type(8)));
typedef float f32x4 __attribute__((ext_vector_type(4)));

__device__ __forceinline__ unsigned short f32_bf16(float f) {
    unsigned u = __float_as_uint(f);
    u += 0x7FFFu + ((u >> 16) & 1u);
    return (unsigned short)(u >> 16);
}
__device__ __forceinline__ float bf16_f32(unsigned short h) {
    return __uint_as_float(((unsigned)h) << 16);
}

#define GLL16(g, l) __builtin_amdgcn_global_load_lds(                       \
        (const __attribute__((address_space(1))) void*)(g),                  \
        (__attribute__((address_space(3))) void*)(l), 16, 0, 0)

// ---------------------------------------------------------------------------
// conv_w: W (2048x1024 f32 row-major) -> B-fragment-tiled hi/lo planes.
// Chunk (ntile, kb, n16) = 16B of 8 consecutive-k halves at column n.
// addr_halves = ((ntile*256 + kb)*16 + n16)*8 + k8
// ---------------------------------------------------------------------------
__global__ __launch_bounds__(256) void conv_w(const float* __restrict__ W,
        unsigned short* __restrict__ hi, unsigned short* __restrict__ lo)
{
    const int t = blockIdx.x * 256 + threadIdx.x;   // 256K threads
    const int n = t & 1023;
    const int kb = t >> 10;                          // 0..255
    unsigned hq[4], lq[4];
#pragma unroll
    for (int p = 0; p < 4; ++p) {
        const float v0 = W[(size_t)(kb * 8 + 2 * p) * 1024 + n];
        const float v1 = W[(size_t)(kb * 8 + 2 * p + 1) * 1024 + n];
        const unsigned short h0 = f32_bf16(v0), h1 = f32_bf16(v1);
        const unsigned short l0 = f32_bf16(v0 - bf16_f32(h0));
        const unsigned short l1 = f32_bf16(v1 - bf16_f32(h1));
        hq[p] = (unsigned)h0 | ((unsigned)h1 << 16);
        lq[p] = (unsigned)l0 | ((unsigned)l1 << 16);
    }
    const size_t c = ((size_t)(n >> 4) * 256 + kb) * 128 + (size_t)(n & 15) * 8;
    *(uint4*)(hi + c) = make_uint4(hq[0], hq[1], hq[2], hq[3]);
    *(uint4*)(lo + c) = make_uint4(lq[0], lq[1], lq[2], lq[3]);
}

// ---------------------------------------------------------------------------
// conv_x: x (8192x2048 f32) -> A-fragment-tiled hi/lo planes (KB = 256).
// addr_halves = ((mtile*256 + kb)*16 + m16)*8 + k8
// ---------------------------------------------------------------------------
__global__ __launch_bounds__(256) void conv_x(const float* __restrict__ X,
        unsigned short* __restrict__ hi, unsigned short* __restrict__ lo)
{
    const size_t t = (size_t)blockIdx.x * 256 + threadIdx.x;  // 8192*256
    const int kb = (int)(t & 255);
    const int m = (int)(t >> 8);
    const float4 f0 = *(const float4*)(X + (size_t)m * 2048 + kb * 8);
    const float4 f1 = *(const float4*)(X + (size_t)m * 2048 + kb * 8 + 4);
    const float v[8] = {f0.x, f0.y, f0.z, f0.w, f1.x, f1.y, f1.z, f1.w};
    unsigned hq[4], lq[4];
#pragma unroll
    for (int p = 0; p < 4; ++p) {
        const unsigned short h0 = f32_bf16(v[2 * p]);
        const unsigned short h1 = f32_bf16(v[2 * p + 1]);
        const unsigned short l0 = f32_bf16(v[2 * p] - bf16_f32(h0));
        const unsigned short l1 = f32_bf16(v[2 * p + 1] - bf16_f32(h1));
        hq[p] = (unsigned)h0 | ((unsigned)h1 << 16);
        lq[p] = (unsigned)l0 | ((unsigned)l1 << 16);
    }
    const size_t c = ((size_t)(m >> 4) * 256 + kb) * 128 + (size_t)(m & 15) * 8;
    *(uint4*)(hi + c) = make_uint4(hq[0], hq[1], hq[2], hq[3]);
    *(uint4*)(lo + c) = make_uint4(lq[0], lq[1], lq[2], lq[3]);
}

// ---------------------------------------------------------------------------
// init_misc: emb table rows 0..5 = W_tok[v]+b_tok, row 6 = start_embed;
// tokidx = 6 (start), rc = 1, nt = 0.  emb stored k-contiguous (1024 halves/row).
// ---------------------------------------------------------------------------
__global__ __launch_bounds__(256) void init_misc(
        const float* __restrict__ Wt, const float* __restrict__ bt,
        const float* __restrict__ se,
        unsigned short* __restrict__ ehi, unsigned short* __restrict__ elo,
        int* __restrict__ tokidx, float* __restrict__ rc, float* __restrict__ nt)
{
    const int t = blockIdx.x * 256 + threadIdx.x;   // 8192
    if (t < 7 * 1024) {
        const int r = t >> 10, k = t & 1023;
        const float v = (r < 6) ? (Wt[(size_t)r * 1024 + k] + bt[k]) : se[k];
        const unsigned short hv = f32_bf16(v);
        ehi[t] = hv;
        elo[t] = f32_bf16(v - bf16_f32(hv));
    }
    tokidx[t] = 6;
    rc[t] = 1.0f;
    nt[t] = 0.0f;
}

// ---------------------------------------------------------------------------
// gemm_bt: 128x128 tile, BK=32, split-bf16 3-pass MFMA.
//   mode 0: encoder. A1 = x planes (KB=256, 64 steps). out: hbuf f32 + h planes.
//   mode 1: z/r fused (grid.x=16). A1 = emb gather (steps 0..31), A2 = h planes.
//           bx<8: z = sigmoid -> outf.  bx>=8: rh = sigmoid*h -> rh planes.
//   mode 2: A1 = emb gather, A2 = rh planes. h = (1-z)h + z*tanh -> hbuf + planes.
// ---------------------------------------------------------------------------
__global__ __launch_bounds__(256, 2)
void gemm_bt(
    const unsigned short* __restrict__ A1_hi, const unsigned short* __restrict__ A1_lo,
    const int* __restrict__ tokidx,
    const unsigned short* __restrict__ A2_hi, const unsigned short* __restrict__ A2_lo,
    const unsigned short* __restrict__ B0_hi, const unsigned short* __restrict__ B0_lo,
    const unsigned short* __restrict__ B1_hi, const unsigned short* __restrict__ B1_lo,
    const float* __restrict__ bias0, const float* __restrict__ bias1,
    const float* __restrict__ zbuf, float* __restrict__ hbuf,
    float* __restrict__ outf,
    unsigned short* __restrict__ ophi, unsigned short* __restrict__ oplo,
    int mode)
{
    __shared__ unsigned short lds[16384];   // 32KB: Ahi|Alo|Bhi|Blo, 4096 halves each

    const int tid = threadIdx.x;
    const int lane = tid & 63;
    const int w = tid >> 6;                 // wave 0..3
    int bx = blockIdx.x;
    const int by = blockIdx.y;

    const unsigned short* Bhi = B0_hi;
    const unsigned short* Blo = B0_lo;
    const float* bias = bias0;
    int isR = 0;
    if (mode == 1 && bx >= 8) { bx -= 8; Bhi = B1_hi; Blo = B1_lo; bias = bias1; isR = 1; }

    const int m0 = by * 128;
    const int n0 = bx * 128;

    // staging assignment: wave w fills A-regions (mtiles) 2w,2w+1 and B-regions 2w,2w+1
    const int gma0 = by * 8 + 2 * w;
    const int gma1 = gma0 + 1;
    const int gnb0 = bx * 8 + 2 * w;
    const int gnb1 = gnb0 + 1;

    unsigned short* dA0h = lds + (2 * w) * 512 + lane * 8;
    unsigned short* dA1h = lds + (2 * w + 1) * 512 + lane * 8;
    unsigned short* dA0l = lds + 4096 + (2 * w) * 512 + lane * 8;
    unsigned short* dA1l = lds + 4096 + (2 * w + 1) * 512 + lane * 8;
    unsigned short* dB0h = lds + 8192 + (2 * w) * 512 + lane * 8;
    unsigned short* dB1h = lds + 8192 + (2 * w + 1) * 512 + lane * 8;
    unsigned short* dB0l = lds + 12288 + (2 * w) * 512 + lane * 8;
    unsigned short* dB1l = lds + 12288 + (2 * w + 1) * 512 + lane * 8;

    int tk0 = 0, tk1 = 0;
    if (tokidx) {
        tk0 = tokidx[m0 + (2 * w) * 16 + (lane & 15)];
        tk1 = tokidx[m0 + (2 * w + 1) * 16 + (lane & 15)];
    }

    f32x4 acc[4][4];
#pragma unroll
    for (int i = 0; i < 4; ++i)
#pragma unroll
        for (int j = 0; j < 4; ++j) acc[i][j] = (f32x4){0.f, 0.f, 0.f, 0.f};

    const int wr = w >> 1, wc = w & 1;
    const int fq = lane >> 4;       // k-block quad
    const int fm = lane & 15;

#pragma unroll 1
    for (int s = 0; s < 64; ++s) {
        __syncthreads();
        // ---- stage A ----
        if (mode == 0) {
            const size_t o0 = ((size_t)gma0 * 256 + s * 4) * 128 + lane * 8;
            const size_t o1 = ((size_t)gma1 * 256 + s * 4) * 128 + lane * 8;
            GLL16(A1_hi + o0, dA0h); GLL16(A1_lo + o0, dA0l);
            GLL16(A1_hi + o1, dA1h); GLL16(A1_lo + o1, dA1l);
        } else if (s < 32) {
            const size_t e0 = (size_t)tk0 * 1024 + (size_t)(s * 4 + fq) * 8;
            const size_t e1 = (size_t)tk1 * 1024 + (size_t)(s * 4 + fq) * 8;
            GLL16(A1_hi + e0, dA0h); GLL16(A1_lo + e0, dA0l);
            GLL16(A1_hi + e1, dA1h); GLL16(A1_lo + e1, dA1l);
        } else {
            const size_t o0 = ((size_t)gma0 * 128 + (s - 32) * 4) * 128 + lane * 8;
            const size_t o1 = ((size_t)gma1 * 128 + (s - 32) * 4) * 128 + lane * 8;
            GLL16(A2_hi + o0, dA0h); GLL16(A2_lo + o0, dA0l);
            GLL16(A2_hi + o1, dA1h); GLL16(A2_lo + o1, dA1l);
        }
        // ---- stage B ----
        {
            const size_t b0 = ((size_t)gnb0 * 256 + s * 4) * 128 + lane * 8;
            const size_t b1 = ((size_t)gnb1 * 256 + s * 4) * 128 + lane * 8;
            GLL16(Bhi + b0, dB0h); GLL16(Blo + b0, dB0l);
            GLL16(Bhi + b1, dB1h); GLL16(Blo + b1, dB1l);
        }
        __syncthreads();

        // ---- fragments + MFMA ----
        bf16x8 ah[4], al[4], bh[4], bl[4];
#pragma unroll
        for (int i = 0; i < 4; ++i) {
            const int ra = (wr * 4 + i) * 512 + fq * 128 + fm * 8;
            ah[i] = *(const bf16x8*)(lds + ra);
            al[i] = *(const bf16x8*)(lds + 4096 + ra);
            const int rb = (wc * 4 + i) * 512 + fq * 128 + fm * 8;
            bh[i] = *(const bf16x8*)(lds + 8192 + rb);
            bl[i] = *(const bf16x8*)(lds + 12288 + rb);
        }
#pragma unroll
        for (int i = 0; i < 4; ++i)
#pragma unroll
            for (int j = 0; j < 4; ++j) {
                acc[i][j] = __builtin_amdgcn_mfma_f32_16x16x32_bf16(ah[i], bh[j], acc[i][j], 0, 0, 0);
                acc[i][j] = __builtin_amdgcn_mfma_f32_16x16x32_bf16(ah[i], bl[j], acc[i][j], 0, 0, 0);
                acc[i][j] = __builtin_amdgcn_mfma_f32_16x16x32_bf16(al[i], bh[j], acc[i][j], 0, 0, 0);
            }
    }

    // ---- epilogue ----
#pragma unroll
    for (int i = 0; i < 4; ++i) {
#pragma unroll
        for (int j = 0; j < 4; ++j) {
            const int col = n0 + wc * 64 + j * 16 + fm;
            const float bv = bias[col];
#pragma unroll
            for (int r = 0; r < 4; ++r) {
                const int row = m0 + wr * 64 + i * 16 + fq * 4 + r;
                const float v = acc[i][j][r] + bv;
                const size_t off = (size_t)row * 1024 + col;
                const size_t pc = ((size_t)(row >> 4) * 128 + (col >> 3)) * 128
                                  + (size_t)(row & 15) * 8 + (col & 7);
                if (mode == 0) {
                    hbuf[off] = v;
                    const unsigned short hv = f32_bf16(v);
                    ophi[pc] = hv;
                    oplo[pc] = f32_bf16(v - bf16_f32(hv));
                } else if (mode == 1) {
                    const float sg = 1.0f / (1.0f + expf(-v));
                    if (!isR) {
                        outf[off] = sg;
                    } else {
                        const float rh = sg * hbuf[off];
                        const unsigned short hv = f32_bf16(rh);
                        ophi[pc] = hv;
                        oplo[pc] = f32_bf16(rh - bf16_f32(hv));
                    }
                } else {
                    const float tv = tanhf(v);
                    const float zv = zbuf[off];
                    const float hn = (1.0f - zv) * hbuf[off] + zv * tv;
                    hbuf[off] = hn;
                    const unsigned short hv = f32_bf16(hn);
                    ophi[pc] = hv;
                    oplo[pc] = f32_bf16(hn - bf16_f32(hv));
                }
            }
        }
    }
}

// ---------------------------------------------------------------------------
// step_tok: one wave per batch row. logits, gumbel argmax, message, rc/nt, tokidx.
// ---------------------------------------------------------------------------
__global__ __launch_bounds__(256)
void step_tok(const float* __restrict__ h,
              const float* __restrict__ W_out, const float* __restrict__ b_out,
              const float* __restrict__ u,
              float* __restrict__ rc, float* __restrict__ nt,
              int* __restrict__ tokidx,
              float* __restrict__ out_msg, float* __restrict__ out_logits,
              float* __restrict__ out_nt, int t)
{
    const int lane = threadIdx.x & 63;
    const int wv = threadIdx.x >> 6;
    const int b = blockIdx.x * 4 + wv;

    const float* hr = h + (size_t)b * H_;
    float s[6] = {0.f, 0.f, 0.f, 0.f, 0.f, 0.f};
#pragma unroll
    for (int i = 0; i < 4; ++i) {
        const int k0 = i * 256 + lane * 4;
        const float4 hv = *(const float4*)(hr + k0);
        const float he[4] = {hv.x, hv.y, hv.z, hv.w};
#pragma unroll
        for (int e = 0; e < 4; ++e) {
            const float* wp = W_out + (size_t)(k0 + e) * V_;
            const float xv = he[e];
#pragma unroll
            for (int v = 0; v < 6; ++v) s[v] = fmaf(xv, wp[v], s[v]);
        }
    }
#pragma unroll
    for (int m = 1; m < 64; m <<= 1) {
#pragma unroll
        for (int v = 0; v < 6; ++v) s[v] += __shfl_xor(s[v], m, 64);
    }

    float lg[6];
#pragma unroll
    for (int v = 0; v < 6; ++v) lg[v] = s[v] + b_out[v];

    const float* ub = u + (size_t)b * V_;
    const float eps = 1e-10f;
    float aa[6];
#pragma unroll
    for (int v = 0; v < 6; ++v) {
        const float g = -logf(-logf(ub[v] + eps) + eps);
        aa[v] = lg[v] + g;  // TAU = 1
    }
    int tok = 0;
    float best = aa[0];
#pragma unroll
    for (int v = 1; v < 6; ++v)
        if (aa[v] > best) { best = aa[v]; tok = v; }

    if (lane == 0) {
        const float rco = rc[b];
#pragma unroll
        for (int v = 0; v < 6; ++v) out_logits[(size_t)b * 6 + v] = lg[v];
#pragma unroll
        for (int v = 0; v < 6; ++v)
            out_msg[(size_t)b * 36 + t * 6 + v] = (v == tok) ? rco : 0.0f;
        const float ntn = nt[b] + rco;
        nt[b] = ntn;
        out_nt[b] = ntn;
        rc[b] = (tok == 5) ? 0.0f : rco;
        tokidx[b] = tok;
    }
}

// ---------------------------------------------------------------------------
extern "C" void kernel_launch(void* const* d_in, const int* in_sizes, int n_in,
                              void* d_out, int out_size, void* d_ws, size_t ws_size,
                              hipStream_t stream)
{
    (void)in_sizes; (void)n_in; (void)out_size; (void)ws_size;
    const float* x       = (const float*)d_in[0];
    const float* u_noise = (const float*)d_in[1];
    const float* W_enc   = (const float*)d_in[2];
    const float* b_enc   = (const float*)d_in[3];
    const float* start_e = (const float*)d_in[4];
    const float* W_tok   = (const float*)d_in[5];
    const float* b_tok   = (const float*)d_in[6];
    const float* Wz      = (const float*)d_in[7];
    const float* bz      = (const float*)d_in[8];
    const float* Wr      = (const float*)d_in[9];
    const float* br      = (const float*)d_in[10];
    const float* Wh      = (const float*)d_in[11];
    const float* bh      = (const float*)d_in[12];
    const float* W_out   = (const float*)d_in[13];
    const float* b_out   = (const float*)d_in[14];

    float* out = (float*)d_out;
    float* out_msg = out;                                   // (B, T*V)
    float* out_logits = out + (size_t)B_ * T_ * V_;         // (T, B, V)
    float* out_nt = out_logits + (size_t)T_ * B_ * V_;      // (B,)

    // ---- workspace layout (160.2 MB) ----
    unsigned short* w16 = (unsigned short*)d_ws;
    const size_t WPL = (size_t)2048 * 1024;                 // halves per weight plane
    unsigned short* wz_hi = w16;
    unsigned short* wz_lo = w16 + WPL;
    unsigned short* wr_hi = w16 + 2 * WPL;
    unsigned short* wr_lo = w16 + 3 * WPL;
    unsigned short* wh_hi = w16 + 4 * WPL;
    unsigned short* wh_lo = w16 + 5 * WPL;
    unsigned short* we_hi = w16 + 6 * WPL;
    unsigned short* we_lo = w16 + 7 * WPL;
    unsigned short* x_hi = w16 + 8 * WPL;                   // @32MB, 32MB
    unsigned short* x_lo = x_hi + (size_t)8192 * 2048;      // @64MB, 32MB
    // aliases (x planes dead after encoder):
    float* zbuf = (float*)x_hi;                             // 32MB
    unsigned short* rh_hi = x_lo;                           // 16MB
    unsigned short* rh_lo = x_lo + (size_t)8192 * 1024;     // 16MB
    float* hbuf = (float*)((char*)d_ws + (size_t)96 * 1024 * 1024);
    unsigned short* h_hi = (unsigned short*)((char*)d_ws + (size_t)128 * 1024 * 1024);
    unsigned short* h_lo = h_hi + (size_t)8192 * 1024;
    unsigned short* emb_hi = (unsigned short*)((char*)d_ws + (size_t)160 * 1024 * 1024);
    unsigned short* emb_lo = emb_hi + 8 * 1024;
    int* tokidx = (int*)(emb_lo + 8 * 1024);
    float* rcb = (float*)(tokidx + 8192);
    float* ntb = rcb + 8192;

    // ---- one-time conversions ----
    conv_w<<<1024, 256, 0, stream>>>(Wz, wz_hi, wz_lo);
    conv_w<<<1024, 256, 0, stream>>>(Wr, wr_hi, wr_lo);
    conv_w<<<1024, 256, 0, stream>>>(Wh, wh_hi, wh_lo);
    conv_w<<<1024, 256, 0, stream>>>(W_enc, we_hi, we_lo);
    conv_x<<<8192, 256, 0, stream>>>(x, x_hi, x_lo);
    init_misc<<<32, 256, 0, stream>>>(W_tok, b_tok, start_e, emb_hi, emb_lo,
                                      tokidx, rcb, ntb);

    // ---- encoder: h0 = x @ W_enc + b_enc ----
    gemm_bt<<<dim3(8, 64), 256, 0, stream>>>(
        x_hi, x_lo, nullptr, nullptr, nullptr,
        we_hi, we_lo, nullptr, nullptr, b_enc, nullptr,
        nullptr, hbuf, nullptr, h_hi, h_lo, 0);

    for (int t = 0; t < T_; ++t) {
        // z = sigmoid([prev|h]@Wz+bz); rh = sigmoid([prev|h]@Wr+br)*h
        gemm_bt<<<dim3(16, 64), 256, 0, stream>>>(
            emb_hi, emb_lo, tokidx, h_hi, h_lo,
            wz_hi, wz_lo, wr_hi, wr_lo, bz, br,
            nullptr, hbuf, zbuf, rh_hi, rh_lo, 1);
        // h = (1-z)h + z*tanh([prev|rh]@Wh+bh)
        gemm_bt<<<dim3(8, 64), 256, 0, stream>>>(
            emb_hi, emb_lo, tokidx, rh_hi, rh_lo,
            wh_hi, wh_lo, nullptr, nullptr, bh, nullptr,
            zbuf, hbuf, nullptr, h_hi, h_lo, 2);
        // logits / gumbel argmax / outputs / tokidx
        step_tok<<<B_ / 4, 256, 0, stream>>>(
            hbuf, W_out, b_out, u_noise + (size_t)t * B_ * V_,
            rcb, ntb, tokidx, out_msg,
            out_logits + (size_t)t * B_ * V_, out_nt, t);
    }
}

// Round 3
// 1947.726 us; speedup vs baseline: 3.7928x; 1.1960x over previous
//
#include <hip/hip_runtime.h>
#include <math.h>

#define B_ 8192
#define DIN_ 2048
#define H_ 1024
#define V_ 6
#define T_ 6

typedef short bf16x8 __attribute__((ext_vector_type(8)));
typedef float f32x4 __attribute__((ext_vector_type(4)));

__device__ __forceinline__ unsigned short f32_bf16(float f) {
    unsigned u = __float_as_uint(f);
    u += 0x7FFFu + ((u >> 16) & 1u);
    return (unsigned short)(u >> 16);
}
__device__ __forceinline__ float bf16_f32(unsigned short h) {
    return __uint_as_float(((unsigned)h) << 16);
}

#define GLL16(g, l) __builtin_amdgcn_global_load_lds(                       \
        (const __attribute__((address_space(1))) void*)(g),                  \
        (__attribute__((address_space(3))) void*)(l), 16, 0, 0)

// ---------------------------------------------------------------------------
// conv_w: full 2048x1024 f32 W -> fragment planes, NKB=256 (W_enc only).
// plane addr (halves) = ((n>>4)*NKB + kb)*128 + (n&15)*8 + k8
// ---------------------------------------------------------------------------
__global__ __launch_bounds__(256) void conv_w(const float* __restrict__ W,
        unsigned short* __restrict__ hi, unsigned short* __restrict__ lo)
{
    const int t = blockIdx.x * 256 + threadIdx.x;   // 256K
    const int n = t & 1023;
    const int kb = t >> 10;                          // 0..255
    unsigned hq[4], lq[4];
#pragma unroll
    for (int p = 0; p < 4; ++p) {
        const float v0 = W[(size_t)(kb * 8 + 2 * p) * 1024 + n];
        const float v1 = W[(size_t)(kb * 8 + 2 * p + 1) * 1024 + n];
        const unsigned short h0 = f32_bf16(v0), h1 = f32_bf16(v1);
        const unsigned short l0 = f32_bf16(v0 - bf16_f32(h0));
        const unsigned short l1 = f32_bf16(v1 - bf16_f32(h1));
        hq[p] = (unsigned)h0 | ((unsigned)h1 << 16);
        lq[p] = (unsigned)l0 | ((unsigned)l1 << 16);
    }
    const size_t c = ((size_t)(n >> 4) * 256 + kb) * 128 + (size_t)(n & 15) * 8;
    *(uint4*)(hi + c) = make_uint4(hq[0], hq[1], hq[2], hq[3]);
    *(uint4*)(lo + c) = make_uint4(lq[0], lq[1], lq[2], lq[3]);
}

// ---------------------------------------------------------------------------
// conv_wb: BOTTOM half (rows 1024..2047) of 2048x1024 W -> planes, NKB=128.
// ---------------------------------------------------------------------------
__global__ __launch_bounds__(256) void conv_wb(const float* __restrict__ W,
        unsigned short* __restrict__ hi, unsigned short* __restrict__ lo)
{
    const int t = blockIdx.x * 256 + threadIdx.x;   // 128K
    const int n = t & 1023;
    const int kb = t >> 10;                          // 0..127
    unsigned hq[4], lq[4];
#pragma unroll
    for (int p = 0; p < 4; ++p) {
        const float v0 = W[(size_t)(1024 + kb * 8 + 2 * p) * 1024 + n];
        const float v1 = W[(size_t)(1024 + kb * 8 + 2 * p + 1) * 1024 + n];
        const unsigned short h0 = f32_bf16(v0), h1 = f32_bf16(v1);
        const unsigned short l0 = f32_bf16(v0 - bf16_f32(h0));
        const unsigned short l1 = f32_bf16(v1 - bf16_f32(h1));
        hq[p] = (unsigned)h0 | ((unsigned)h1 << 16);
        lq[p] = (unsigned)l0 | ((unsigned)l1 << 16);
    }
    const size_t c = ((size_t)(n >> 4) * 128 + kb) * 128 + (size_t)(n & 15) * 8;
    *(uint4*)(hi + c) = make_uint4(hq[0], hq[1], hq[2], hq[3]);
    *(uint4*)(lo + c) = make_uint4(lq[0], lq[1], lq[2], lq[3]);
}

// ---------------------------------------------------------------------------
// conv_x: x (8192x2048 f32) -> A planes, NKB=256.
// ---------------------------------------------------------------------------
__global__ __launch_bounds__(256) void conv_x(const float* __restrict__ X,
        unsigned short* __restrict__ hi, unsigned short* __restrict__ lo)
{
    const size_t t = (size_t)blockIdx.x * 256 + threadIdx.x;  // 8192*256
    const int kb = (int)(t & 255);
    const int m = (int)(t >> 8);
    const float4 f0 = *(const float4*)(X + (size_t)m * 2048 + kb * 8);
    const float4 f1 = *(const float4*)(X + (size_t)m * 2048 + kb * 8 + 4);
    const float v[8] = {f0.x, f0.y, f0.z, f0.w, f1.x, f1.y, f1.z, f1.w};
    unsigned hq[4], lq[4];
#pragma unroll
    for (int p = 0; p < 4; ++p) {
        const unsigned short h0 = f32_bf16(v[2 * p]);
        const unsigned short h1 = f32_bf16(v[2 * p + 1]);
        const unsigned short l0 = f32_bf16(v[2 * p] - bf16_f32(h0));
        const unsigned short l1 = f32_bf16(v[2 * p + 1] - bf16_f32(h1));
        hq[p] = (unsigned)h0 | ((unsigned)h1 << 16);
        lq[p] = (unsigned)l0 | ((unsigned)l1 << 16);
    }
    const size_t c = ((size_t)(m >> 4) * 256 + kb) * 128 + (size_t)(m & 15) * 8;
    *(uint4*)(hi + c) = make_uint4(hq[0], hq[1], hq[2], hq[3]);
    *(uint4*)(lo + c) = make_uint4(lq[0], lq[1], lq[2], lq[3]);
}

// ---------------------------------------------------------------------------
// prep_tables: P_m[tok][n] = sum_k emb[tok][k] * W_m[k][n] + b_m[n]
// (top halves k<1024, exact f32). emb rows: 0..5 = W_tok[v]+b_tok, 6 = start.
// grid (4, 3): n-block x matrix.
// ---------------------------------------------------------------------------
__global__ __launch_bounds__(256) void prep_tables(
        const float* __restrict__ Wz, const float* __restrict__ Wr,
        const float* __restrict__ Wh,
        const float* __restrict__ bz, const float* __restrict__ br,
        const float* __restrict__ bh,
        const float* __restrict__ Wt, const float* __restrict__ bt,
        const float* __restrict__ se,
        float* __restrict__ Pz, float* __restrict__ Pr, float* __restrict__ Ph)
{
    __shared__ float emb[7][1024];
    const int tid = threadIdx.x;
    for (int i = tid; i < 7 * 1024; i += 256) {
        const int r = i >> 10, k = i & 1023;
        emb[r][k] = (r < 6) ? (Wt[(size_t)r * 1024 + k] + bt[k]) : se[k];
    }
    __syncthreads();
    const float* W = (blockIdx.y == 0) ? Wz : ((blockIdx.y == 1) ? Wr : Wh);
    const float* bb = (blockIdx.y == 0) ? bz : ((blockIdx.y == 1) ? br : bh);
    float* P = (blockIdx.y == 0) ? Pz : ((blockIdx.y == 1) ? Pr : Ph);
    const int n = blockIdx.x * 256 + tid;
    float acc[7] = {0.f, 0.f, 0.f, 0.f, 0.f, 0.f, 0.f};
    for (int k = 0; k < 1024; ++k) {
        const float wv = W[(size_t)k * 1024 + n];
#pragma unroll
        for (int r = 0; r < 7; ++r) acc[r] = fmaf(emb[r][k], wv, acc[r]);
    }
    const float bvv = bb[n];
#pragma unroll
    for (int r = 0; r < 7; ++r) P[(size_t)r * 1024 + n] = acc[r] + bvv;
}

// ---------------------------------------------------------------------------
// init_misc: tokidx = 6 (start), rc = 1, nt = 0.
// ---------------------------------------------------------------------------
__global__ __launch_bounds__(256) void init_misc(
        int* __restrict__ tokidx, float* __restrict__ rc, float* __restrict__ nt)
{
    const int t = blockIdx.x * 256 + threadIdx.x;   // 8192
    tokidx[t] = 6;
    rc[t] = 1.0f;
    nt[t] = 0.0f;
}

// ---------------------------------------------------------------------------
// gemm_bt: 128x128 tile, BK=32, split-bf16 3-pass MFMA, K = nkb*8.
//   mode 0: encoder. nkb=256. v = acc + P0[col]. out: hbuf + planes.
//   mode 1: z/r (grid.x=16). nkb=128. v = acc + P[tok[row]][col].
//           bx<8: z = sigmoid(v) -> outf.  bx>=8: rh = sigmoid(v)*h -> planes.
//   mode 2: nkb=128. h = (1-z)h + z*tanh(acc + Ph[tok[row]][col]) -> hbuf+planes.
// ---------------------------------------------------------------------------
__global__ __launch_bounds__(256, 2)
void gemm_bt(
    const unsigned short* __restrict__ A_hi, const unsigned short* __restrict__ A_lo,
    const unsigned short* __restrict__ B0_hi, const unsigned short* __restrict__ B0_lo,
    const unsigned short* __restrict__ B1_hi, const unsigned short* __restrict__ B1_lo,
    const float* __restrict__ P0, const float* __restrict__ P1,
    const int* __restrict__ tokidx,
    const float* __restrict__ zbuf, float* __restrict__ hbuf,
    float* __restrict__ outf,
    unsigned short* __restrict__ ophi, unsigned short* __restrict__ oplo,
    int nkb, int mode)
{
    __shared__ unsigned short lds[16384];   // 32KB: Ahi|Alo|Bhi|Blo

    const int tid = threadIdx.x;
    const int lane = tid & 63;
    const int w = tid >> 6;
    int bx = blockIdx.x;
    const int by = blockIdx.y;

    const unsigned short* Bhi = B0_hi;
    const unsigned short* Blo = B0_lo;
    const float* Pm = P0;
    int isR = 0;
    if (mode == 1 && bx >= 8) { bx -= 8; Bhi = B1_hi; Blo = B1_lo; Pm = P1; isR = 1; }

    const int m0 = by * 128;
    const int n0 = bx * 128;
    const int gma0 = by * 8 + 2 * w;
    const int gnb0 = bx * 8 + 2 * w;

    unsigned short* dA0h = lds + (2 * w) * 512 + lane * 8;
    unsigned short* dA1h = lds + (2 * w + 1) * 512 + lane * 8;
    unsigned short* dA0l = lds + 4096 + (2 * w) * 512 + lane * 8;
    unsigned short* dA1l = lds + 4096 + (2 * w + 1) * 512 + lane * 8;
    unsigned short* dB0h = lds + 8192 + (2 * w) * 512 + lane * 8;
    unsigned short* dB1h = lds + 8192 + (2 * w + 1) * 512 + lane * 8;
    unsigned short* dB0l = lds + 12288 + (2 * w) * 512 + lane * 8;
    unsigned short* dB1l = lds + 12288 + (2 * w + 1) * 512 + lane * 8;

    f32x4 acc[4][4];
#pragma unroll
    for (int i = 0; i < 4; ++i)
#pragma unroll
        for (int j = 0; j < 4; ++j) acc[i][j] = (f32x4){0.f, 0.f, 0.f, 0.f};

    const int wr = w >> 1, wc = w & 1;
    const int fq = lane >> 4;
    const int fm = lane & 15;
    const int nsteps = nkb >> 2;

#pragma unroll 1
    for (int s = 0; s < nsteps; ++s) {
        __syncthreads();
        const size_t o0 = ((size_t)gma0 * nkb + s * 4) * 128 + lane * 8;
        const size_t o1 = o0 + (size_t)nkb * 128;
        GLL16(A_hi + o0, dA0h); GLL16(A_lo + o0, dA0l);
        GLL16(A_hi + o1, dA1h); GLL16(A_lo + o1, dA1l);
        const size_t b0 = ((size_t)gnb0 * nkb + s * 4) * 128 + lane * 8;
        const size_t b1 = b0 + (size_t)nkb * 128;
        GLL16(Bhi + b0, dB0h); GLL16(Blo + b0, dB0l);
        GLL16(Bhi + b1, dB1h); GLL16(Blo + b1, dB1l);
        __syncthreads();

        bf16x8 ah[4], al[4], bh4[4], bl4[4];
#pragma unroll
        for (int i = 0; i < 4; ++i) {
            const int ra = (wr * 4 + i) * 512 + fq * 128 + fm * 8;
            ah[i] = *(const bf16x8*)(lds + ra);
            al[i] = *(const bf16x8*)(lds + 4096 + ra);
            const int rb = (wc * 4 + i) * 512 + fq * 128 + fm * 8;
            bh4[i] = *(const bf16x8*)(lds + 8192 + rb);
            bl4[i] = *(const bf16x8*)(lds + 12288 + rb);
        }
#pragma unroll
        for (int i = 0; i < 4; ++i)
#pragma unroll
            for (int j = 0; j < 4; ++j) {
                acc[i][j] = __builtin_amdgcn_mfma_f32_16x16x32_bf16(ah[i], bh4[j], acc[i][j], 0, 0, 0);
                acc[i][j] = __builtin_amdgcn_mfma_f32_16x16x32_bf16(ah[i], bl4[j], acc[i][j], 0, 0, 0);
                acc[i][j] = __builtin_amdgcn_mfma_f32_16x16x32_bf16(al[i], bh4[j], acc[i][j], 0, 0, 0);
            }
    }

    // ---- epilogue ----
#pragma unroll
    for (int i = 0; i < 4; ++i) {
        int toks[4];
#pragma unroll
        for (int r = 0; r < 4; ++r) {
            const int row = m0 + wr * 64 + i * 16 + fq * 4 + r;
            toks[r] = tokidx ? tokidx[row] : 0;
        }
#pragma unroll
        for (int j = 0; j < 4; ++j) {
            const int col = n0 + wc * 64 + j * 16 + fm;
#pragma unroll
            for (int r = 0; r < 4; ++r) {
                const int row = m0 + wr * 64 + i * 16 + fq * 4 + r;
                const float v = acc[i][j][r] + Pm[(size_t)toks[r] * 1024 + col];
                const size_t off = (size_t)row * 1024 + col;
                const size_t pc = ((size_t)(row >> 4) * 128 + (col >> 3)) * 128
                                  + (size_t)(row & 15) * 8 + (col & 7);
                if (mode == 0) {
                    hbuf[off] = v;
                    const unsigned short hv = f32_bf16(v);
                    ophi[pc] = hv;
                    oplo[pc] = f32_bf16(v - bf16_f32(hv));
                } else if (mode == 1) {
                    const float sg = 1.0f / (1.0f + expf(-v));
                    if (!isR) {
                        outf[off] = sg;
                    } else {
                        const float rh = sg * hbuf[off];
                        const unsigned short hv = f32_bf16(rh);
                        ophi[pc] = hv;
                        oplo[pc] = f32_bf16(rh - bf16_f32(hv));
                    }
                } else {
                    const float tv = tanhf(v);
                    const float zv = zbuf[off];
                    const float hn = (1.0f - zv) * hbuf[off] + zv * tv;
                    hbuf[off] = hn;
                    const unsigned short hv = f32_bf16(hn);
                    ophi[pc] = hv;
                    oplo[pc] = f32_bf16(hn - bf16_f32(hv));
                }
            }
        }
    }
}

// ---------------------------------------------------------------------------
// step_tok: one wave per batch row.
// ---------------------------------------------------------------------------
__global__ __launch_bounds__(256)
void step_tok(const float* __restrict__ h,
              const float* __restrict__ W_out, const float* __restrict__ b_out,
              const float* __restrict__ u,
              float* __restrict__ rc, float* __restrict__ nt,
              int* __restrict__ tokidx,
              float* __restrict__ out_msg, float* __restrict__ out_logits,
              float* __restrict__ out_nt, int t)
{
    const int lane = threadIdx.x & 63;
    const int wv = threadIdx.x >> 6;
    const int b = blockIdx.x * 4 + wv;

    const float* hr = h + (size_t)b * H_;
    float s[6] = {0.f, 0.f, 0.f, 0.f, 0.f, 0.f};
#pragma unroll
    for (int i = 0; i < 4; ++i) {
        const int k0 = i * 256 + lane * 4;
        const float4 hv = *(const float4*)(hr + k0);
        const float he[4] = {hv.x, hv.y, hv.z, hv.w};
#pragma unroll
        for (int e = 0; e < 4; ++e) {
            const float* wp = W_out + (size_t)(k0 + e) * V_;
            const float xv = he[e];
#pragma unroll
            for (int v = 0; v < 6; ++v) s[v] = fmaf(xv, wp[v], s[v]);
        }
    }
#pragma unroll
    for (int m = 1; m < 64; m <<= 1) {
#pragma unroll
        for (int v = 0; v < 6; ++v) s[v] += __shfl_xor(s[v], m, 64);
    }

    float lg[6];
#pragma unroll
    for (int v = 0; v < 6; ++v) lg[v] = s[v] + b_out[v];

    const float* ub = u + (size_t)b * V_;
    const float eps = 1e-10f;
    float aa[6];
#pragma unroll
    for (int v = 0; v < 6; ++v) {
        const float g = -logf(-logf(ub[v] + eps) + eps);
        aa[v] = lg[v] + g;  // TAU = 1
    }
    int tok = 0;
    float best = aa[0];
#pragma unroll
    for (int v = 1; v < 6; ++v)
        if (aa[v] > best) { best = aa[v]; tok = v; }

    if (lane == 0) {
        const float rco = rc[b];
#pragma unroll
        for (int v = 0; v < 6; ++v) out_logits[(size_t)b * 6 + v] = lg[v];
#pragma unroll
        for (int v = 0; v < 6; ++v)
            out_msg[(size_t)b * 36 + t * 6 + v] = (v == tok) ? rco : 0.0f;
        const float ntn = nt[b] + rco;
        nt[b] = ntn;
        out_nt[b] = ntn;
        rc[b] = (tok == 5) ? 0.0f : rco;
        tokidx[b] = tok;
    }
}

// ---------------------------------------------------------------------------
extern "C" void kernel_launch(void* const* d_in, const int* in_sizes, int n_in,
                              void* d_out, int out_size, void* d_ws, size_t ws_size,
                              hipStream_t stream)
{
    (void)in_sizes; (void)n_in; (void)out_size; (void)ws_size;
    const float* x       = (const float*)d_in[0];
    const float* u_noise = (const float*)d_in[1];
    const float* W_enc   = (const float*)d_in[2];
    const float* b_enc   = (const float*)d_in[3];
    const float* start_e = (const float*)d_in[4];
    const float* W_tok   = (const float*)d_in[5];
    const float* b_tok   = (const float*)d_in[6];
    const float* Wz      = (const float*)d_in[7];
    const float* bz      = (const float*)d_in[8];
    const float* Wr      = (const float*)d_in[9];
    const float* br      = (const float*)d_in[10];
    const float* Wh      = (const float*)d_in[11];
    const float* bh      = (const float*)d_in[12];
    const float* W_out   = (const float*)d_in[13];
    const float* b_out   = (const float*)d_in[14];

    float* out = (float*)d_out;
    float* out_msg = out;                                   // (B, T*V)
    float* out_logits = out + (size_t)B_ * T_ * V_;         // (T, B, V)
    float* out_nt = out_logits + (size_t)T_ * B_ * V_;      // (B,)

    // ---- workspace layout (~148.1 MB) ----
    char* wsb = (char*)d_ws;
    const size_t MB = 1024 * 1024;
    unsigned short* wzb_hi = (unsigned short*)(wsb + 0 * MB);    // 2MB each
    unsigned short* wzb_lo = (unsigned short*)(wsb + 2 * MB);
    unsigned short* wrb_hi = (unsigned short*)(wsb + 4 * MB);
    unsigned short* wrb_lo = (unsigned short*)(wsb + 6 * MB);
    unsigned short* whb_hi = (unsigned short*)(wsb + 8 * MB);
    unsigned short* whb_lo = (unsigned short*)(wsb + 10 * MB);
    unsigned short* we_hi  = (unsigned short*)(wsb + 12 * MB);   // 4MB
    unsigned short* we_lo  = (unsigned short*)(wsb + 16 * MB);   // 4MB
    unsigned short* x_hi   = (unsigned short*)(wsb + 20 * MB);   // 32MB
    unsigned short* x_lo   = (unsigned short*)(wsb + 52 * MB);   // 32MB
    float*  zbuf  = (float*)(wsb + 20 * MB);                     // alias x_hi
    unsigned short* rh_hi  = (unsigned short*)(wsb + 52 * MB);   // alias x_lo
    unsigned short* rh_lo  = (unsigned short*)(wsb + 68 * MB);
    float*  hbuf  = (float*)(wsb + 84 * MB);                     // 32MB
    unsigned short* h_hi   = (unsigned short*)(wsb + 116 * MB);  // 16MB
    unsigned short* h_lo   = (unsigned short*)(wsb + 132 * MB);  // 16MB
    float* Pz = (float*)(wsb + 148 * MB);                        // 7x1024 each
    float* Pr = Pz + 7 * 1024;
    float* Ph = Pr + 7 * 1024;
    int* tokidx = (int*)(Ph + 7 * 1024);
    float* rcb = (float*)(tokidx + B_);
    float* ntb = rcb + B_;

    // ---- one-time conversions / tables ----
    conv_wb<<<512, 256, 0, stream>>>(Wz, wzb_hi, wzb_lo);
    conv_wb<<<512, 256, 0, stream>>>(Wr, wrb_hi, wrb_lo);
    conv_wb<<<512, 256, 0, stream>>>(Wh, whb_hi, whb_lo);
    conv_w<<<1024, 256, 0, stream>>>(W_enc, we_hi, we_lo);
    conv_x<<<8192, 256, 0, stream>>>(x, x_hi, x_lo);
    prep_tables<<<dim3(4, 3), 256, 0, stream>>>(Wz, Wr, Wh, bz, br, bh,
                                                W_tok, b_tok, start_e, Pz, Pr, Ph);
    init_misc<<<32, 256, 0, stream>>>(tokidx, rcb, ntb);

    // ---- encoder: h0 = x @ W_enc + b_enc (K=2048) ----
    gemm_bt<<<dim3(8, 64), 256, 0, stream>>>(
        x_hi, x_lo, we_hi, we_lo, nullptr, nullptr,
        b_enc, nullptr, nullptr,
        nullptr, hbuf, nullptr, h_hi, h_lo, 256, 0);

    for (int t = 0; t < T_; ++t) {
        // z = sigmoid(h@Wz_bot + Pz[tok]); rh = sigmoid(h@Wr_bot + Pr[tok]) * h
        gemm_bt<<<dim3(16, 64), 256, 0, stream>>>(
            h_hi, h_lo, wzb_hi, wzb_lo, wrb_hi, wrb_lo,
            Pz, Pr, tokidx,
            nullptr, hbuf, zbuf, rh_hi, rh_lo, 128, 1);
        // h = (1-z)h + z*tanh(rh@Wh_bot + Ph[tok])
        gemm_bt<<<dim3(8, 64), 256, 0, stream>>>(
            rh_hi, rh_lo, whb_hi, whb_lo, nullptr, nullptr,
            Ph, nullptr, tokidx,
            zbuf, hbuf, nullptr, h_hi, h_lo, 128, 2);
        // logits / gumbel argmax / outputs / tokidx
        step_tok<<<B_ / 4, 256, 0, stream>>>(
            hbuf, W_out, b_out, u_noise + (size_t)t * B_ * V_,
            rcb, ntb, tokidx, out_msg,
            out_logits + (size_t)t * B_ * V_, out_nt, t);
    }
}

// Round 4
// 1809.461 us; speedup vs baseline: 4.0826x; 1.0764x over previous
//
#include <hip/hip_runtime.h>
#include <math.h>

#define B_ 8192
#define DIN_ 2048
#define H_ 1024
#define V_ 6
#define T_ 6

typedef short bf16x8 __attribute__((ext_vector_type(8)));
typedef float f32x4 __attribute__((ext_vector_type(4)));

__device__ __forceinline__ unsigned short f32_bf16(float f) {
    unsigned u = __float_as_uint(f);
    u += 0x7FFFu + ((u >> 16) & 1u);
    return (unsigned short)(u >> 16);
}
__device__ __forceinline__ float bf16_f32(unsigned short h) {
    return __uint_as_float(((unsigned)h) << 16);
}

#define GLL16(g, l) __builtin_amdgcn_global_load_lds(                       \
        (const __attribute__((address_space(1))) void*)(g),                  \
        (__attribute__((address_space(3))) void*)(l), 16, 0, 0)

// ---------------------------------------------------------------------------
// conv_w: full 2048x1024 f32 W -> fragment planes, NKB=256 (W_enc only).
// plane addr (halves) = ((n>>4)*NKB + kb)*128 + (n&15)*8 + k8
// ---------------------------------------------------------------------------
__global__ __launch_bounds__(256) void conv_w(const float* __restrict__ W,
        unsigned short* __restrict__ hi, unsigned short* __restrict__ lo)
{
    const int t = blockIdx.x * 256 + threadIdx.x;   // 256K
    const int n = t & 1023;
    const int kb = t >> 10;                          // 0..255
    unsigned hq[4], lq[4];
#pragma unroll
    for (int p = 0; p < 4; ++p) {
        const float v0 = W[(size_t)(kb * 8 + 2 * p) * 1024 + n];
        const float v1 = W[(size_t)(kb * 8 + 2 * p + 1) * 1024 + n];
        const unsigned short h0 = f32_bf16(v0), h1 = f32_bf16(v1);
        const unsigned short l0 = f32_bf16(v0 - bf16_f32(h0));
        const unsigned short l1 = f32_bf16(v1 - bf16_f32(h1));
        hq[p] = (unsigned)h0 | ((unsigned)h1 << 16);
        lq[p] = (unsigned)l0 | ((unsigned)l1 << 16);
    }
    const size_t c = ((size_t)(n >> 4) * 256 + kb) * 128 + (size_t)(n & 15) * 8;
    *(uint4*)(hi + c) = make_uint4(hq[0], hq[1], hq[2], hq[3]);
    *(uint4*)(lo + c) = make_uint4(lq[0], lq[1], lq[2], lq[3]);
}

// ---------------------------------------------------------------------------
// conv_wb: BOTTOM half (rows 1024..2047) of 2048x1024 W -> planes, NKB=128.
// ---------------------------------------------------------------------------
__global__ __launch_bounds__(256) void conv_wb(const float* __restrict__ W,
        unsigned short* __restrict__ hi, unsigned short* __restrict__ lo)
{
    const int t = blockIdx.x * 256 + threadIdx.x;   // 128K
    const int n = t & 1023;
    const int kb = t >> 10;                          // 0..127
    unsigned hq[4], lq[4];
#pragma unroll
    for (int p = 0; p < 4; ++p) {
        const float v0 = W[(size_t)(1024 + kb * 8 + 2 * p) * 1024 + n];
        const float v1 = W[(size_t)(1024 + kb * 8 + 2 * p + 1) * 1024 + n];
        const unsigned short h0 = f32_bf16(v0), h1 = f32_bf16(v1);
        const unsigned short l0 = f32_bf16(v0 - bf16_f32(h0));
        const unsigned short l1 = f32_bf16(v1 - bf16_f32(h1));
        hq[p] = (unsigned)h0 | ((unsigned)h1 << 16);
        lq[p] = (unsigned)l0 | ((unsigned)l1 << 16);
    }
    const size_t c = ((size_t)(n >> 4) * 128 + kb) * 128 + (size_t)(n & 15) * 8;
    *(uint4*)(hi + c) = make_uint4(hq[0], hq[1], hq[2], hq[3]);
    *(uint4*)(lo + c) = make_uint4(lq[0], lq[1], lq[2], lq[3]);
}

// ---------------------------------------------------------------------------
// conv_x: x (8192x2048 f32) -> A planes, NKB=256.
// ---------------------------------------------------------------------------
__global__ __launch_bounds__(256) void conv_x(const float* __restrict__ X,
        unsigned short* __restrict__ hi, unsigned short* __restrict__ lo)
{
    const size_t t = (size_t)blockIdx.x * 256 + threadIdx.x;  // 8192*256
    const int kb = (int)(t & 255);
    const int m = (int)(t >> 8);
    const float4 f0 = *(const float4*)(X + (size_t)m * 2048 + kb * 8);
    const float4 f1 = *(const float4*)(X + (size_t)m * 2048 + kb * 8 + 4);
    const float v[8] = {f0.x, f0.y, f0.z, f0.w, f1.x, f1.y, f1.z, f1.w};
    unsigned hq[4], lq[4];
#pragma unroll
    for (int p = 0; p < 4; ++p) {
        const unsigned short h0 = f32_bf16(v[2 * p]);
        const unsigned short h1 = f32_bf16(v[2 * p + 1]);
        const unsigned short l0 = f32_bf16(v[2 * p] - bf16_f32(h0));
        const unsigned short l1 = f32_bf16(v[2 * p + 1] - bf16_f32(h1));
        hq[p] = (unsigned)h0 | ((unsigned)h1 << 16);
        lq[p] = (unsigned)l0 | ((unsigned)l1 << 16);
    }
    const size_t c = ((size_t)(m >> 4) * 256 + kb) * 128 + (size_t)(m & 15) * 8;
    *(uint4*)(hi + c) = make_uint4(hq[0], hq[1], hq[2], hq[3]);
    *(uint4*)(lo + c) = make_uint4(lq[0], lq[1], lq[2], lq[3]);
}

// ---------------------------------------------------------------------------
// prep_tables: P_m[tok][n] = sum_k emb[tok][k] * W_m[k][n] + b_m[n]
// ---------------------------------------------------------------------------
__global__ __launch_bounds__(256) void prep_tables(
        const float* __restrict__ Wz, const float* __restrict__ Wr,
        const float* __restrict__ Wh,
        const float* __restrict__ bz, const float* __restrict__ br,
        const float* __restrict__ bh,
        const float* __restrict__ Wt, const float* __restrict__ bt,
        const float* __restrict__ se,
        float* __restrict__ Pz, float* __restrict__ Pr, float* __restrict__ Ph)
{
    __shared__ float emb[7][1024];
    const int tid = threadIdx.x;
    for (int i = tid; i < 7 * 1024; i += 256) {
        const int r = i >> 10, k = i & 1023;
        emb[r][k] = (r < 6) ? (Wt[(size_t)r * 1024 + k] + bt[k]) : se[k];
    }
    __syncthreads();
    const float* W = (blockIdx.y == 0) ? Wz : ((blockIdx.y == 1) ? Wr : Wh);
    const float* bb = (blockIdx.y == 0) ? bz : ((blockIdx.y == 1) ? br : bh);
    float* P = (blockIdx.y == 0) ? Pz : ((blockIdx.y == 1) ? Pr : Ph);
    const int n = blockIdx.x * 256 + tid;
    float acc[7] = {0.f, 0.f, 0.f, 0.f, 0.f, 0.f, 0.f};
    for (int k = 0; k < 1024; ++k) {
        const float wv = W[(size_t)k * 1024 + n];
#pragma unroll
        for (int r = 0; r < 7; ++r) acc[r] = fmaf(emb[r][k], wv, acc[r]);
    }
    const float bvv = bb[n];
#pragma unroll
    for (int r = 0; r < 7; ++r) P[(size_t)r * 1024 + n] = acc[r] + bvv;
}

// ---------------------------------------------------------------------------
// init_misc: tokidx = 6 (start), rc = 1, nt = 0.
// ---------------------------------------------------------------------------
__global__ __launch_bounds__(256) void init_misc(
        int* __restrict__ tokidx, float* __restrict__ rc, float* __restrict__ nt)
{
    const int t = blockIdx.x * 256 + threadIdx.x;   // 8192
    tokidx[t] = 6;
    rc[t] = 1.0f;
    nt[t] = 0.0f;
}

// ---------------------------------------------------------------------------
// gemm_bt: 128x128 tile, BK=32, split-bf16 3-pass MFMA, K = nkb*8.
// Launch bounds (256,3): 3 blocks/CU (96KB LDS, 140 regs <= 170). Round-3
// evidence: (256,2) left MfmaUtil at 21% with everything idle = overlap-bound.
// XCD swizzle: linear wg id % 8 = XCD (heuristic); each XCD gets a contiguous
// 8-wide by-band with bx fastest so co-resident blocks share one A-band in L2.
// ---------------------------------------------------------------------------
__global__ __launch_bounds__(256, 3)
void gemm_bt(
    const unsigned short* __restrict__ A_hi, const unsigned short* __restrict__ A_lo,
    const unsigned short* __restrict__ B0_hi, const unsigned short* __restrict__ B0_lo,
    const unsigned short* __restrict__ B1_hi, const unsigned short* __restrict__ B1_lo,
    const float* __restrict__ P0, const float* __restrict__ P1,
    const int* __restrict__ tokidx,
    const float* __restrict__ zbuf, float* __restrict__ hbuf,
    float* __restrict__ outf,
    unsigned short* __restrict__ ophi, unsigned short* __restrict__ oplo,
    int nkb, int mode)
{
    __shared__ unsigned short lds[16384];   // 32KB: Ahi|Alo|Bhi|Blo

    const int tid = threadIdx.x;
    const int lane = tid & 63;
    const int w = tid >> 6;

    // ---- XCD-aware swizzle (bijective relabel of the NX x 64 grid) ----
    const int NX = gridDim.x;
    const int lin = blockIdx.y * NX + blockIdx.x;
    const int xcd = lin & 7;
    const int idx = lin >> 3;                // 0 .. NX*8-1
    int bx = idx % NX;                       // fastest: co-resident share by
    const int by = xcd * 8 + idx / NX;       // contiguous by-band per XCD

    const unsigned short* Bhi = B0_hi;
    const unsigned short* Blo = B0_lo;
    const float* Pm = P0;
    int isR = 0;
    if (mode == 1 && bx >= 8) { bx -= 8; Bhi = B1_hi; Blo = B1_lo; Pm = P1; isR = 1; }

    const int m0 = by * 128;
    const int n0 = bx * 128;
    const int gma0 = by * 8 + 2 * w;
    const int gnb0 = bx * 8 + 2 * w;

    unsigned short* dA0h = lds + (2 * w) * 512 + lane * 8;
    unsigned short* dA1h = lds + (2 * w + 1) * 512 + lane * 8;
    unsigned short* dA0l = lds + 4096 + (2 * w) * 512 + lane * 8;
    unsigned short* dA1l = lds + 4096 + (2 * w + 1) * 512 + lane * 8;
    unsigned short* dB0h = lds + 8192 + (2 * w) * 512 + lane * 8;
    unsigned short* dB1h = lds + 8192 + (2 * w + 1) * 512 + lane * 8;
    unsigned short* dB0l = lds + 12288 + (2 * w) * 512 + lane * 8;
    unsigned short* dB1l = lds + 12288 + (2 * w + 1) * 512 + lane * 8;

    f32x4 acc[4][4];
#pragma unroll
    for (int i = 0; i < 4; ++i)
#pragma unroll
        for (int j = 0; j < 4; ++j) acc[i][j] = (f32x4){0.f, 0.f, 0.f, 0.f};

    const int wr = w >> 1, wc = w & 1;
    const int fq = lane >> 4;
    const int fm = lane & 15;
    const int nsteps = nkb >> 2;

#pragma unroll 1
    for (int s = 0; s < nsteps; ++s) {
        __syncthreads();
        const size_t o0 = ((size_t)gma0 * nkb + s * 4) * 128 + lane * 8;
        const size_t o1 = o0 + (size_t)nkb * 128;
        GLL16(A_hi + o0, dA0h); GLL16(A_lo + o0, dA0l);
        GLL16(A_hi + o1, dA1h); GLL16(A_lo + o1, dA1l);
        const size_t b0 = ((size_t)gnb0 * nkb + s * 4) * 128 + lane * 8;
        const size_t b1 = b0 + (size_t)nkb * 128;
        GLL16(Bhi + b0, dB0h); GLL16(Blo + b0, dB0l);
        GLL16(Bhi + b1, dB1h); GLL16(Blo + b1, dB1l);
        __syncthreads();

        bf16x8 ah[4], al[4], bh4[4], bl4[4];
#pragma unroll
        for (int i = 0; i < 4; ++i) {
            const int ra = (wr * 4 + i) * 512 + fq * 128 + fm * 8;
            ah[i] = *(const bf16x8*)(lds + ra);
            al[i] = *(const bf16x8*)(lds + 4096 + ra);
            const int rb = (wc * 4 + i) * 512 + fq * 128 + fm * 8;
            bh4[i] = *(const bf16x8*)(lds + 8192 + rb);
            bl4[i] = *(const bf16x8*)(lds + 12288 + rb);
        }
#pragma unroll
        for (int i = 0; i < 4; ++i)
#pragma unroll
            for (int j = 0; j < 4; ++j) {
                acc[i][j] = __builtin_amdgcn_mfma_f32_16x16x32_bf16(ah[i], bh4[j], acc[i][j], 0, 0, 0);
                acc[i][j] = __builtin_amdgcn_mfma_f32_16x16x32_bf16(ah[i], bl4[j], acc[i][j], 0, 0, 0);
                acc[i][j] = __builtin_amdgcn_mfma_f32_16x16x32_bf16(al[i], bh4[j], acc[i][j], 0, 0, 0);
            }
    }

    // ---- epilogue ----
#pragma unroll
    for (int i = 0; i < 4; ++i) {
        int toks[4];
#pragma unroll
        for (int r = 0; r < 4; ++r) {
            const int row = m0 + wr * 64 + i * 16 + fq * 4 + r;
            toks[r] = tokidx ? tokidx[row] : 0;
        }
#pragma unroll
        for (int j = 0; j < 4; ++j) {
            const int col = n0 + wc * 64 + j * 16 + fm;
#pragma unroll
            for (int r = 0; r < 4; ++r) {
                const int row = m0 + wr * 64 + i * 16 + fq * 4 + r;
                const float v = acc[i][j][r] + Pm[(size_t)toks[r] * 1024 + col];
                const size_t off = (size_t)row * 1024 + col;
                const size_t pc = ((size_t)(row >> 4) * 128 + (col >> 3)) * 128
                                  + (size_t)(row & 15) * 8 + (col & 7);
                if (mode == 0) {
                    hbuf[off] = v;
                    const unsigned short hv = f32_bf16(v);
                    ophi[pc] = hv;
                    oplo[pc] = f32_bf16(v - bf16_f32(hv));
                } else if (mode == 1) {
                    const float sg = 1.0f / (1.0f + expf(-v));
                    if (!isR) {
                        outf[off] = sg;
                    } else {
                        const float rh = sg * hbuf[off];
                        const unsigned short hv = f32_bf16(rh);
                        ophi[pc] = hv;
                        oplo[pc] = f32_bf16(rh - bf16_f32(hv));
                    }
                } else {
                    const float tv = tanhf(v);
                    const float zv = zbuf[off];
                    const float hn = (1.0f - zv) * hbuf[off] + zv * tv;
                    hbuf[off] = hn;
                    const unsigned short hv = f32_bf16(hn);
                    ophi[pc] = hv;
                    oplo[pc] = f32_bf16(hn - bf16_f32(hv));
                }
            }
        }
    }
}

// ---------------------------------------------------------------------------
// step_tok: one wave per batch row.
// ---------------------------------------------------------------------------
__global__ __launch_bounds__(256)
void step_tok(const float* __restrict__ h,
              const float* __restrict__ W_out, const float* __restrict__ b_out,
              const float* __restrict__ u,
              float* __restrict__ rc, float* __restrict__ nt,
              int* __restrict__ tokidx,
              float* __restrict__ out_msg, float* __restrict__ out_logits,
              float* __restrict__ out_nt, int t)
{
    const int lane = threadIdx.x & 63;
    const int wv = threadIdx.x >> 6;
    const int b = blockIdx.x * 4 + wv;

    const float* hr = h + (size_t)b * H_;
    float s[6] = {0.f, 0.f, 0.f, 0.f, 0.f, 0.f};
#pragma unroll
    for (int i = 0; i < 4; ++i) {
        const int k0 = i * 256 + lane * 4;
        const float4 hv = *(const float4*)(hr + k0);
        const float he[4] = {hv.x, hv.y, hv.z, hv.w};
#pragma unroll
        for (int e = 0; e < 4; ++e) {
            const float* wp = W_out + (size_t)(k0 + e) * V_;
            const float xv = he[e];
#pragma unroll
            for (int v = 0; v < 6; ++v) s[v] = fmaf(xv, wp[v], s[v]);
        }
    }
#pragma unroll
    for (int m = 1; m < 64; m <<= 1) {
#pragma unroll
        for (int v = 0; v < 6; ++v) s[v] += __shfl_xor(s[v], m, 64);
    }

    float lg[6];
#pragma unroll
    for (int v = 0; v < 6; ++v) lg[v] = s[v] + b_out[v];

    const float* ub = u + (size_t)b * V_;
    const float eps = 1e-10f;
    float aa[6];
#pragma unroll
    for (int v = 0; v < 6; ++v) {
        const float g = -logf(-logf(ub[v] + eps) + eps);
        aa[v] = lg[v] + g;  // TAU = 1
    }
    int tok = 0;
    float best = aa[0];
#pragma unroll
    for (int v = 1; v < 6; ++v)
        if (aa[v] > best) { best = aa[v]; tok = v; }

    if (lane == 0) {
        const float rco = rc[b];
#pragma unroll
        for (int v = 0; v < 6; ++v) out_logits[(size_t)b * 6 + v] = lg[v];
#pragma unroll
        for (int v = 0; v < 6; ++v)
            out_msg[(size_t)b * 36 + t * 6 + v] = (v == tok) ? rco : 0.0f;
        const float ntn = nt[b] + rco;
        nt[b] = ntn;
        out_nt[b] = ntn;
        rc[b] = (tok == 5) ? 0.0f : rco;
        tokidx[b] = tok;
    }
}

// ---------------------------------------------------------------------------
extern "C" void kernel_launch(void* const* d_in, const int* in_sizes, int n_in,
                              void* d_out, int out_size, void* d_ws, size_t ws_size,
                              hipStream_t stream)
{
    (void)in_sizes; (void)n_in; (void)out_size; (void)ws_size;
    const float* x       = (const float*)d_in[0];
    const float* u_noise = (const float*)d_in[1];
    const float* W_enc   = (const float*)d_in[2];
    const float* b_enc   = (const float*)d_in[3];
    const float* start_e = (const float*)d_in[4];
    const float* W_tok   = (const float*)d_in[5];
    const float* b_tok   = (const float*)d_in[6];
    const float* Wz      = (const float*)d_in[7];
    const float* bz      = (const float*)d_in[8];
    const float* Wr      = (const float*)d_in[9];
    const float* br      = (const float*)d_in[10];
    const float* Wh      = (const float*)d_in[11];
    const float* bh      = (const float*)d_in[12];
    const float* W_out   = (const float*)d_in[13];
    const float* b_out   = (const float*)d_in[14];

    float* out = (float*)d_out;
    float* out_msg = out;                                   // (B, T*V)
    float* out_logits = out + (size_t)B_ * T_ * V_;         // (T, B, V)
    float* out_nt = out_logits + (size_t)T_ * B_ * V_;      // (B,)

    // ---- workspace layout (~148.1 MB) ----
    char* wsb = (char*)d_ws;
    const size_t MB = 1024 * 1024;
    unsigned short* wzb_hi = (unsigned short*)(wsb + 0 * MB);    // 2MB each
    unsigned short* wzb_lo = (unsigned short*)(wsb + 2 * MB);
    unsigned short* wrb_hi = (unsigned short*)(wsb + 4 * MB);
    unsigned short* wrb_lo = (unsigned short*)(wsb + 6 * MB);
    unsigned short* whb_hi = (unsigned short*)(wsb + 8 * MB);
    unsigned short* whb_lo = (unsigned short*)(wsb + 10 * MB);
    unsigned short* we_hi  = (unsigned short*)(wsb + 12 * MB);   // 4MB
    unsigned short* we_lo  = (unsigned short*)(wsb + 16 * MB);   // 4MB
    unsigned short* x_hi   = (unsigned short*)(wsb + 20 * MB);   // 32MB
    unsigned short* x_lo   = (unsigned short*)(wsb + 52 * MB);   // 32MB
    float*  zbuf  = (float*)(wsb + 20 * MB);                     // alias x_hi
    unsigned short* rh_hi  = (unsigned short*)(wsb + 52 * MB);   // alias x_lo
    unsigned short* rh_lo  = (unsigned short*)(wsb + 68 * MB);
    float*  hbuf  = (float*)(wsb + 84 * MB);                     // 32MB
    unsigned short* h_hi   = (unsigned short*)(wsb + 116 * MB);  // 16MB
    unsigned short* h_lo   = (unsigned short*)(wsb + 132 * MB);  // 16MB
    float* Pz = (float*)(wsb + 148 * MB);                        // 7x1024 each
    float* Pr = Pz + 7 * 1024;
    float* Ph = Pr + 7 * 1024;
    int* tokidx = (int*)(Ph + 7 * 1024);
    float* rcb = (float*)(tokidx + B_);
    float* ntb = rcb + B_;

    // ---- one-time conversions / tables ----
    conv_wb<<<512, 256, 0, stream>>>(Wz, wzb_hi, wzb_lo);
    conv_wb<<<512, 256, 0, stream>>>(Wr, wrb_hi, wrb_lo);
    conv_wb<<<512, 256, 0, stream>>>(Wh, whb_hi, whb_lo);
    conv_w<<<1024, 256, 0, stream>>>(W_enc, we_hi, we_lo);
    conv_x<<<8192, 256, 0, stream>>>(x, x_hi, x_lo);
    prep_tables<<<dim3(4, 3), 256, 0, stream>>>(Wz, Wr, Wh, bz, br, bh,
                                                W_tok, b_tok, start_e, Pz, Pr, Ph);
    init_misc<<<32, 256, 0, stream>>>(tokidx, rcb, ntb);

    // ---- encoder: h0 = x @ W_enc + b_enc (K=2048) ----
    gemm_bt<<<dim3(8, 64), 256, 0, stream>>>(
        x_hi, x_lo, we_hi, we_lo, nullptr, nullptr,
        b_enc, nullptr, nullptr,
        nullptr, hbuf, nullptr, h_hi, h_lo, 256, 0);

    for (int t = 0; t < T_; ++t) {
        // z = sigmoid(h@Wz_bot + Pz[tok]); rh = sigmoid(h@Wr_bot + Pr[tok]) * h
        gemm_bt<<<dim3(16, 64), 256, 0, stream>>>(
            h_hi, h_lo, wzb_hi, wzb_lo, wrb_hi, wrb_lo,
            Pz, Pr, tokidx,
            nullptr, hbuf, zbuf, rh_hi, rh_lo, 128, 1);
        // h = (1-z)h + z*tanh(rh@Wh_bot + Ph[tok])
        gemm_bt<<<dim3(8, 64), 256, 0, stream>>>(
            rh_hi, rh_lo, whb_hi, whb_lo, nullptr, nullptr,
            Ph, nullptr, tokidx,
            zbuf, hbuf, nullptr, h_hi, h_lo, 128, 2);
        // logits / gumbel argmax / outputs / tokidx
        step_tok<<<B_ / 4, 256, 0, stream>>>(
            hbuf, W_out, b_out, u_noise + (size_t)t * B_ * V_,
            rcb, ntb, tokidx, out_msg,
            out_logits + (size_t)t * B_ * V_, out_nt, t);
    }
}